// Round 21
// baseline (203.502 us; speedup 1.0000x reference)
//
#include <hip/hip_runtime.h>
#include <hip/hip_bf16.h>
#include <math.h>

typedef unsigned int u32;
typedef unsigned short u16;
typedef __attribute__((ext_vector_type(8))) short short8v;   // 8 bf16 (4 VGPRs)
typedef __attribute__((ext_vector_type(4))) float f32x4;     // 4 fp32

#define HH 256
#define WW 256
#define HP 128
#define WP 128
#define NPTS (8*HP*WP)        // 131072 pooled points
#define NPIX 524288           // 8*256*256 per-channel pixel count (both BNs)
#define Y_ELEMS (8*3*HH*WW)   // 1572864
#define IDX_OFF Y_ELEMS
#define LOSS_OFF (Y_ELEMS + NPTS)
#define MARGIN_MFMA 0.05f     // sc-units; m-units flag threshold = MARGIN_MFMA/2

__device__ __forceinline__ u32 bfr(float f) {   // f32 -> bf16 bits (RNE)
  u32 u = __float_as_uint(f);
  return (u + 0x7FFFu + ((u >> 16) & 1u)) >> 16;
}
__device__ __forceinline__ float bff(u32 h) { return __uint_as_float(h << 16); }

// ============ K1: f32 conv1 (LDS-staged x) -> BN-stats partials + pooled raw-max ============
// In-wave stats butterfly in f32 (err ~1e-7 rel, << flag margin); f64 from cross-wave stage on.
__global__ __launch_bounds__(256) void k1_fused(
    const float* __restrict__ x, const float* __restrict__ w1,
    const float* __restrict__ b1, double* __restrict__ part1,
    float* __restrict__ pooled) {
  __shared__ float wl[27*64];     // [tap][ch]
  __shared__ float b1s[64];
  __shared__ float xs[3][4][68];  // [ic][row r][col j], zero-padded at edges
  __shared__ double sred[4][128];
  int t = threadIdx.x;
  for (int i = t; i < 27*64; i += 256) { int c = i & 63; int tap = i >> 6; wl[i] = w1[c*27 + tap]; }
  if (t < 64) b1s[t] = b1[t];
  int bx = blockIdx.x;
  int b = bx >> 9;
  int pid0 = (bx & 511) * 32;
  int py = pid0 >> 7;
  int px0 = pid0 & 127;
  int gcol0 = 2*px0 - 1, grow0 = 2*py - 1;
  for (int i = t; i < 816; i += 256) {          // 3*4*68
    int j = i % 68;
    int rr = (i / 68) & 3;
    int ic = i / 272;
    int col = gcol0 + j, row = grow0 + rr;
    float v = 0.f;
    if (col >= 0 && col < WW && row >= 0 && row < HH)
      v = x[((size_t)((b*3 + ic)*HH + row))*WW + col];
    xs[ic][rr][j] = v;
  }
  __syncthreads();
  int lpx = t >> 3;
  int co = (t & 7) * 8;
  float A0[8], A1[8], C0[8], C1[8];
  #pragma unroll
  for (int c = 0; c < 8; ++c) { float bb = b1s[co + c]; A0[c] = bb; A1[c] = bb; C0[c] = bb; C1[c] = bb; }
  #pragma unroll
  for (int ic = 0; ic < 3; ++ic) {
    #pragma unroll
    for (int dy = 0; dy < 3; ++dy) {
      const float* wb = wl + (size_t)((ic*3 + dy)*3)*64 + co;
      int j0 = 2*lpx;
      float xa0 = xs[ic][dy][j0+0], xa1 = xs[ic][dy][j0+1], xa2 = xs[ic][dy][j0+2], xa3 = xs[ic][dy][j0+3];
      float xc0 = xs[ic][dy+1][j0+0], xc1 = xs[ic][dy+1][j0+1], xc2 = xs[ic][dy+1][j0+2], xc3 = xs[ic][dy+1][j0+3];
      #pragma unroll
      for (int c = 0; c < 8; ++c) {
        float w0 = wb[c], w1v = wb[64 + c], w2v = wb[128 + c];
        A0[c] = fmaf(xa0, w0, fmaf(xa1, w1v, fmaf(xa2, w2v, A0[c])));
        A1[c] = fmaf(xa1, w0, fmaf(xa2, w1v, fmaf(xa3, w2v, A1[c])));
        C0[c] = fmaf(xc0, w0, fmaf(xc1, w1v, fmaf(xc2, w2v, C0[c])));
        C1[c] = fmaf(xc1, w0, fmaf(xc2, w1v, fmaf(xc3, w2v, C1[c])));
      }
    }
  }
  float fs[8], fq[8], m[8];
  #pragma unroll
  for (int c = 0; c < 8; ++c) {
    float a0 = A0[c], a1 = A1[c], c0 = C0[c], c1 = C1[c];
    fs[c] = (a0 + a1) + (c0 + c1);
    float q_ = fmaf(a0, a0, 0.f);
    q_ = fmaf(a1, a1, q_);
    q_ = fmaf(c0, c0, q_);
    q_ = fmaf(c1, c1, q_);
    fq[c] = q_;
    m[c] = fmaxf(fmaxf(a0, a1), fmaxf(c0, c1));
  }
  int pid = pid0 + lpx;
  size_t p = (size_t)b*16384 + pid;
  *(float4*)(pooled + p*64 + co)     = make_float4(m[0], m[1], m[2], m[3]);
  *(float4*)(pooled + p*64 + co + 4) = make_float4(m[4], m[5], m[6], m[7]);
  #pragma unroll 1
  for (int c = 0; c < 8; ++c) {
    #pragma unroll
    for (int st = 8; st < 64; st <<= 1) {
      fs[c] += __shfl_xor(fs[c], st, 64);
      fq[c] += __shfl_xor(fq[c], st, 64);
    }
  }
  int w = t >> 6;
  if ((t & 63) < 8) {
    #pragma unroll
    for (int c = 0; c < 8; ++c) {
      sred[w][co + c] = (double)fs[c];
      sred[w][64 + co + c] = (double)fq[c];
    }
  }
  __syncthreads();
  if (t < 128)
    part1[(size_t)bx*128 + t] = (sred[0][t] + sred[1][t]) + (sred[2][t] + sred[3][t]);
}

// K2: blocks 0-63: reduce 4096 block-partials (f64) -> A,B per channel.
// blocks 64-79: build weff[combo16][ic64][oc4] from w2 (independent of part1). grid 80.
__global__ __launch_bounds__(256) void k2_reduce_bn1(
    const double* __restrict__ part1, const float* __restrict__ gamma,
    const float* __restrict__ beta, double* __restrict__ sAB1,
    const float* __restrict__ w2, float* __restrict__ weff) {
  int bx = blockIdx.x;
  if (bx >= 64) {
    int e = (bx - 64)*256 + threadIdx.x;
    int oc = e & 3;
    int ic = (e >> 2) & 63;
    int combo = e >> 8;
    if (oc == 3) { weff[e] = 0.f; return; }
    int bq = combo & 1, a = (combo >> 1) & 1, ex = (combo >> 2) & 1, ey = combo >> 3;
    int rs = (a == 0) ? 0 : (ey == 0 ? 1 : 2);
    int rc = ((a ^ ey) != 0) ? 2 : 1;
    int cs = (bq == 0) ? 0 : (ex == 0 ? 1 : 2);
    int cc = ((bq ^ ex) != 0) ? 2 : 1;
    float ssum = 0.f;
    for (int i = 0; i < rc; ++i)
      for (int j = 0; j < cc; ++j)
        ssum += w2[((oc*64 + ic)*3 + (rs + i))*3 + (cs + j)];
    weff[e] = ssum;
    return;
  }
  int c = bx, t = threadIdx.x;
  double s = 0.0, q = 0.0;
  for (int i = t; i < 4096; i += 256) {
    const double* p = part1 + (size_t)i*128;
    s += p[c];
    q += p[64 + c];
  }
  __shared__ double ls[256], lq[256];
  ls[t] = s; lq[t] = q;
  __syncthreads();
  for (int o = 128; o > 0; o >>= 1) {
    if (t < o) { ls[t] += ls[t+o]; lq[t] += lq[t+o]; }
    __syncthreads();
  }
  if (t == 0) {
    double mean = ls[0] / (double)NPIX;
    double var  = lq[0] / (double)NPIX - mean*mean;
    double A = (double)gamma[c] / sqrt(var + 1e-5);
    sAB1[c] = A;
    sAB1[64 + c] = (double)beta[c] - mean*A;
  }
}

// kE_prep: blocks 0-3: embed -> tile-fragment-lane-linear bf16 hi/lo pack + enormd + enf
// (+flagcnt zero). blocks 4-259: proj table (reads weff from k2). grid 260 x 256.
__global__ void kE_prep(const float* __restrict__ embed, char* __restrict__ epack,
                        double* __restrict__ enormd, float* __restrict__ enf,
                        u32* __restrict__ flagcnt,
                        const float* __restrict__ weff, float* __restrict__ proj) {
  int bxx = blockIdx.x;
  if (bxx >= 4) {
    int e = (bxx - 4)*256 + threadIdx.x;
    int k = e >> 6;
    int slot = e & 63;
    int combo = slot >> 2, oc = slot & 3;
    if (oc == 3) { proj[e] = 0.f; return; }
    const float* er = embed + (size_t)k*64;
    const float* wc = weff + combo*256 + oc;
    float s0 = 0.f, s1 = 0.f;
    #pragma unroll 8
    for (int ic = 0; ic < 64; ic += 2) {
      s0 = fmaf(er[ic],     wc[ic*4],     s0);
      s1 = fmaf(er[ic + 1], wc[ic*4 + 4], s1);
    }
    proj[e] = s0 + s1;
    return;
  }
  if (bxx == 0 && threadIdx.x == 0) flagcnt[0] = 0u;
  int k = bxx*256 + threadIdx.x;
  const float4* e4 = (const float4*)(embed + (size_t)k*64);
  u32 hw[32], lw[32];
  double s0 = 0.0, s1 = 0.0;
  #pragma unroll
  for (int i = 0; i < 16; ++i) {
    float4 v = e4[i];
    float f0 = v.x, f1 = v.y, f2 = v.z, f3 = v.w;
    s0 = fma((double)f0, (double)f0, s0); s1 = fma((double)f1, (double)f1, s1);
    s0 = fma((double)f2, (double)f2, s0); s1 = fma((double)f3, (double)f3, s1);
    u32 h0 = bfr(f0), h1 = bfr(f1), h2 = bfr(f2), h3 = bfr(f3);
    u32 l0 = bfr(f0 - bff(h0)), l1 = bfr(f1 - bff(h1));
    u32 l2 = bfr(f2 - bff(h2)), l3 = bfr(f3 - bff(h3));
    hw[2*i]   = h0 | (h1 << 16);
    hw[2*i+1] = h2 | (h3 << 16);
    lw[2*i]   = l0 | (l1 << 16);
    lw[2*i+1] = l2 | (l3 << 16);
  }
  char* tb = epack + (size_t)(k >> 4)*4096 + (size_t)(k & 15)*16;
  #pragma unroll
  for (int g = 0; g < 4; ++g) {
    *(uint4*)(tb + 0*1024 + g*256) = make_uint4(hw[4*g+0], hw[4*g+1], hw[4*g+2], hw[4*g+3]);
    *(uint4*)(tb + 1*1024 + g*256) = make_uint4(hw[16+4*g+0], hw[16+4*g+1], hw[16+4*g+2], hw[16+4*g+3]);
    *(uint4*)(tb + 2*1024 + g*256) = make_uint4(lw[4*g+0], lw[4*g+1], lw[4*g+2], lw[4*g+3]);
    *(uint4*)(tb + 3*1024 + g*256) = make_uint4(lw[16+4*g+0], lw[16+4*g+1], lw[16+4*g+2], lw[16+4*g+3]);
  }
  double e = s0 + s1;
  enormd[k] = e;
  enf[k] = (float)e;
}

// KB-MFMA v9: fused feature pack + 4-tiles-per-barrier B staging + med3 tracking + setprio.
#define MFMA_BF16 __builtin_amdgcn_mfma_f32_16x16x32_bf16
#define PROC_T(ntv) { \
  int code = (ntv)*16 + col; \
  float en2 = senf[code];   /* pre-negated-halved: -en/2 */ \
  f32x4 accA0={en2,en2,en2,en2}, accA1={0.f,0.f,0.f,0.f}; \
  f32x4 accB0={en2,en2,en2,en2}, accB1={0.f,0.f,0.f,0.f}; \
  __builtin_amdgcn_s_setprio(1); \
  accA0 = MFMA_BF16(aA_h0, b_h0, accA0, 0, 0, 0); \
  accA1 = MFMA_BF16(aA_h1, b_h1, accA1, 0, 0, 0); \
  accB0 = MFMA_BF16(aB_h0, b_h0, accB0, 0, 0, 0); \
  accB1 = MFMA_BF16(aB_h1, b_h1, accB1, 0, 0, 0); \
  accA0 = MFMA_BF16(aA_l0, b_h0, accA0, 0, 0, 0); \
  accA1 = MFMA_BF16(aA_l1, b_h1, accA1, 0, 0, 0); \
  accB0 = MFMA_BF16(aB_l0, b_h0, accB0, 0, 0, 0); \
  accB1 = MFMA_BF16(aB_l1, b_h1, accB1, 0, 0, 0); \
  accA0 = MFMA_BF16(aA_h0, b_l0, accA0, 0, 0, 0); \
  accA1 = MFMA_BF16(aA_h1, b_l1, accA1, 0, 0, 0); \
  accB0 = MFMA_BF16(aB_h0, b_l0, accB0, 0, 0, 0); \
  accB1 = MFMA_BF16(aB_h1, b_l1, accB1, 0, 0, 0); \
  __builtin_amdgcn_s_setprio(0); \
  _Pragma("unroll") \
  for (int j = 0; j < 4; ++j) { \
    float mA = accA0[j] + accA1[j]; \
    bool cA = mA > bestA[j]; \
    b2A[j] = __builtin_amdgcn_fmed3f(b2A[j], mA, bestA[j]);  /* b2<=best => median == max(b2,min(m,best)) */ \
    bestA[j] = fmaxf(bestA[j], mA); \
    idxA[j] = cA ? code : idxA[j]; \
    float mB = accB0[j] + accB1[j]; \
    bool cB = mB > bestB[j]; \
    b2B[j] = __builtin_amdgcn_fmed3f(b2B[j], mB, bestB[j]); \
    bestB[j] = fmaxf(bestB[j], mB); \
    idxB[j] = cB ? code : idxB[j]; \
  } \
}
#define PROC_LDS(bb, ntv) { \
  short8v b_h0 = *(const short8v*)((bb) + 0*1024 + lane*16); \
  short8v b_h1 = *(const short8v*)((bb) + 1*1024 + lane*16); \
  short8v b_l0 = *(const short8v*)((bb) + 2*1024 + lane*16); \
  short8v b_l1 = *(const short8v*)((bb) + 3*1024 + lane*16); \
  PROC_T(ntv); \
}

__global__ __launch_bounds__(256) void kB_mfma(
    const float* __restrict__ pooled, const double* __restrict__ sAB1,
    const char* __restrict__ epack, const float* __restrict__ enf,
    int* __restrict__ idxbuf, float* __restrict__ out_f, double* __restrict__ lossq,
    u32* __restrict__ flagcnt, u32* __restrict__ flagids) {
  __shared__ float senf[1024];
  __shared__ char shbuf[32768];   // phase1: 128 pts x 256B features; phase2: btile[2][4][4096]
  __shared__ float fnp[256];
  __shared__ float fnsum[128];
  __shared__ float sAs[64], sBs[64];
  __shared__ double wred[4];
  int t = threadIdx.x;
  for (int i = t; i < 1024; i += 256) senf[i] = -0.5f * enf[i];
  if (t < 64) { sAs[t] = (float)sAB1[t]; sBs[t] = (float)sAB1[64 + t]; }
  __syncthreads();
  // ---- phase 1: feature BN+relu+bf16 hi/lo split for this block's 128 points, staged in LDS ----
  {
    int lp = t >> 1, h = t & 1, cb = h*32;
    int p = blockIdx.x*128 + lp;
    const float4* src = (const float4*)(pooled + (size_t)p*64 + cb);
    float fn = 0.f;
    u32 hw[16], lw[16];
    #pragma unroll
    for (int i = 0; i < 8; ++i) {
      float4 v = src[i];
      float f0 = fmaxf(fmaf(v.x, sAs[cb+4*i+0], sBs[cb+4*i+0]), 0.f);
      float f1 = fmaxf(fmaf(v.y, sAs[cb+4*i+1], sBs[cb+4*i+1]), 0.f);
      float f2 = fmaxf(fmaf(v.z, sAs[cb+4*i+2], sBs[cb+4*i+2]), 0.f);
      float f3 = fmaxf(fmaf(v.w, sAs[cb+4*i+3], sBs[cb+4*i+3]), 0.f);
      fn = fmaf(f0, f0, fn); fn = fmaf(f1, f1, fn);
      fn = fmaf(f2, f2, fn); fn = fmaf(f3, f3, fn);
      u32 h0 = bfr(f0), h1 = bfr(f1), h2 = bfr(f2), h3 = bfr(f3);
      u32 l0 = bfr(f0 - bff(h0)), l1 = bfr(f1 - bff(h1));
      u32 l2 = bfr(f2 - bff(h2)), l3 = bfr(f3 - bff(h3));
      hw[2*i]   = h0 | (h1 << 16);
      hw[2*i+1] = h2 | (h3 << 16);
      lw[2*i]   = l0 | (l1 << 16);
      lw[2*i+1] = l2 | (l3 << 16);
    }
    uint4* dh = (uint4*)(shbuf + (size_t)lp*256 + h*64);        // hi half (point-major layout)
    uint4* dl = (uint4*)(shbuf + (size_t)lp*256 + 128 + h*64);  // lo half
    #pragma unroll
    for (int i = 0; i < 4; ++i) dh[i] = make_uint4(hw[4*i], hw[4*i+1], hw[4*i+2], hw[4*i+3]);
    #pragma unroll
    for (int i = 0; i < 4; ++i) dl[i] = make_uint4(lw[4*i], lw[4*i+1], lw[4*i+2], lw[4*i+3]);
    fnp[t] = fn;
  }
  __syncthreads();
  if ((t & 1) == 0) fnsum[t >> 1] = fnp[t] + fnp[t + 1];
  // ---- A fragments from staged features ----
  int lane = t & 63;
  int col = lane & 15, g = lane >> 4;
  int w = t >> 6;
  const char* fbA = shbuf + (size_t)(w*32 + col)*256 + 16*g;
  const char* fbB = shbuf + (size_t)(w*32 + 16 + col)*256 + 16*g;
  short8v aA_h0 = *(const short8v*)(fbA);
  short8v aA_h1 = *(const short8v*)(fbA + 64);
  short8v aA_l0 = *(const short8v*)(fbA + 128);
  short8v aA_l1 = *(const short8v*)(fbA + 192);
  short8v aB_h0 = *(const short8v*)(fbB);
  short8v aB_h1 = *(const short8v*)(fbB + 64);
  short8v aB_l0 = *(const short8v*)(fbB + 128);
  short8v aB_l1 = *(const short8v*)(fbB + 192);
  __syncthreads();   // all fragment reads + fnsum writes done before shbuf reuse as btile
  char (*btile)[4][4096] = (char (*)[4][4096])shbuf;   // double-buffered 4-tile group (64 codes)
  float bestA[4], b2A[4], bestB[4], b2B[4];
  int idxA[4], idxB[4];
  #pragma unroll
  for (int j = 0; j < 4; ++j) {
    bestA[j] = -3.4e38f; b2A[j] = -3.4e38f; idxA[j] = 0;
    bestB[j] = -3.4e38f; b2B[j] = -3.4e38f; idxB[j] = 0;
  }
  // prologue: stage group 0 (tiles 0..3)
  #pragma unroll
  for (int k = 0; k < 4; ++k)
    *(uint4*)(&btile[0][k][t*16]) = *(const uint4*)(epack + (size_t)k*4096 + (size_t)t*16);
  __syncthreads();
  #pragma unroll 1
  for (int ng = 0; ng < 16; ++ng) {
    int cur = ng & 1;
    uint4 stg0, stg1, stg2, stg3;
    if (ng < 15) {
      const char* base = epack + (size_t)(4*ng + 4)*4096 + (size_t)t*16;
      stg0 = *(const uint4*)(base);             // issue early — latency hidden under 4x PROC
      stg1 = *(const uint4*)(base + 4096);
      stg2 = *(const uint4*)(base + 8192);
      stg3 = *(const uint4*)(base + 12288);
    }
    PROC_LDS(&btile[cur][0][0], 4*ng + 0);
    PROC_LDS(&btile[cur][1][0], 4*ng + 1);
    PROC_LDS(&btile[cur][2][0], 4*ng + 2);
    PROC_LDS(&btile[cur][3][0], 4*ng + 3);
    if (ng < 15) {
      *(uint4*)(&btile[cur ^ 1][0][t*16]) = stg0;   // write-late
      *(uint4*)(&btile[cur ^ 1][1][t*16]) = stg1;
      *(uint4*)(&btile[cur ^ 1][2][t*16]) = stg2;
      *(uint4*)(&btile[cur ^ 1][3][t*16]) = stg3;
    }
    __syncthreads();
  }
  // cross-lane reduce over 16 col-lanes per row-group (maximize m; lowest idx on ties = np rule)
  double lsum = 0.0;
  #pragma unroll
  for (int grp = 0; grp < 2; ++grp) {
    #pragma unroll
    for (int j = 0; j < 4; ++j) {
      float b  = (grp == 0) ? bestA[j] : bestB[j];
      float s2 = (grp == 0) ? b2A[j]   : b2B[j];
      int  id  = (grp == 0) ? idxA[j]  : idxB[j];
      #pragma unroll
      for (int m = 1; m < 16; m <<= 1) {
        float ob  = __shfl_xor(b, m, 64);
        float os2 = __shfl_xor(s2, m, 64);
        int  oid  = __shfl_xor(id, m, 64);
        s2 = fmaxf(fmaxf(s2, os2), fminf(b, ob));
        if (ob > b || (ob == b && oid < id)) { b = ob; id = oid; }
      }
      if (col == 0) {
        int lpt = w*32 + grp*16 + g*4 + j;
        int p = blockIdx.x*128 + lpt;
        idxbuf[p] = id;
        out_f[IDX_OFF + p] = (float)id;
        lsum += (double)fmaf(-2.f, b, fnsum[lpt]);   // fn + (en - 2 dot)
        if (b - s2 <= 0.5f*MARGIN_MFMA) { u32 pos = atomicAdd(flagcnt, 1u); flagids[pos] = (u32)p; }
      }
    }
  }
  // block loss reduce (fixed-order butterfly, deterministic)
  #pragma unroll
  for (int m = 1; m < 64; m <<= 1) lsum += __shfl_xor(lsum, m, 64);
  if (lane == 0) wred[w] = lsum;
  __syncthreads();
  if (t == 0) lossq[blockIdx.x] = (wred[0] + wred[1]) + (wred[2] + wred[3]);
}

// KC: exact f64 resolution for flagged near-tie points + loss finalize (last block).
__global__ __launch_bounds__(64) void kC_fallback(
    const float* __restrict__ x, const float* __restrict__ w1,
    const float* __restrict__ b1, const double* __restrict__ sAB1,
    const float* __restrict__ embed, const double* __restrict__ enormd,
    const u32* __restrict__ flagcnt, const u32* __restrict__ flagids,
    int* __restrict__ idxbuf, float* __restrict__ out_f,
    const double* __restrict__ lossq) {
  int lane = threadIdx.x;
  if (blockIdx.x == gridDim.x - 1) {   // loss finalize (deterministic fixed order)
    double s = 0.0;
    for (int i = lane; i < 1024; i += 64) s += lossq[i];
    #pragma unroll
    for (int st = 1; st < 64; st <<= 1) s += __shfl_xor(s, st, 64);
    if (lane == 0) out_f[LOSS_OFF] = (float)(0.25 * s / (double)((size_t)NPTS * 64));
    return;
  }
  __shared__ double fd[64];
  double wv[27];
  #pragma unroll
  for (int i = 0; i < 27; ++i) wv[i] = (double)w1[lane*27 + i];
  double bias = (double)b1[lane];
  double A = sAB1[lane], B = sAB1[64 + lane];
  u32 n = flagcnt[0];
  u32 stride = gridDim.x - 1;
  for (u32 i = blockIdx.x; i < n; i += stride) {
    int p = (int)flagids[i];
    int b = p >> 14, py = (p >> 7) & 127, px = p & 127;
    double mx = -1e300;
    #pragma unroll
    for (int ry = 0; ry < 2; ++ry) {
      #pragma unroll
      for (int cx = 0; cx < 2; ++cx) {
        double a = bias;
        int yy = 2*py + ry, xx = 2*px + cx;
        #pragma unroll
        for (int ic = 0; ic < 3; ++ic) {
          #pragma unroll
          for (int dy = 0; dy < 3; ++dy) {
            int ryy = yy + dy - 1;
            if (ryy >= 0 && ryy < HH) {
              const float* row = x + ((size_t)((b*3 + ic)*HH + ryy))*WW;
              #pragma unroll
              for (int dxx = 0; dxx < 3; ++dxx) {
                int xc = xx + dxx - 1;
                if (xc >= 0 && xc < WW) a = fma((double)row[xc], wv[(ic*3 + dy)*3 + dxx], a);
              }
            }
          }
        }
        mx = fmax(mx, a);
      }
    }
    fd[lane] = fmax(fma(mx, A, B), 0.0);
    __syncthreads();
    double bd = 1e300; int bk = 1 << 20;
    for (int kk = 0; kk < 16; ++kk) {
      int k = kk*64 + lane;
      const float* e = embed + (size_t)k*64;
      double e0=0,e1=0,e2=0,e3=0;
      #pragma unroll
      for (int d = 0; d < 16; ++d) {
        e0 = fma(fd[4*d+0], (double)e[4*d+0], e0);
        e1 = fma(fd[4*d+1], (double)e[4*d+1], e1);
        e2 = fma(fd[4*d+2], (double)e[4*d+2], e2);
        e3 = fma(fd[4*d+3], (double)e[4*d+3], e3);
      }
      double dist = fma(-2.0, (e0+e1)+(e2+e3), enormd[k]);
      if (dist < bd) { bd = dist; bk = k; }
    }
    #pragma unroll
    for (int st = 1; st < 64; st <<= 1) {
      double od = __shfl_xor(bd, st, 64);
      int ok = __shfl_xor(bk, st, 64);
      if (od < bd || (od == bd && ok < bk)) { bd = od; bk = ok; }
    }
    if (lane == 0) {
      idxbuf[p] = bk;
      out_f[IDX_OFF + p] = (float)bk;
    }
    __syncthreads();
  }
}

// conv2 v4: per-cell proj-table lookup. MODE 0: stats. MODE 1: stats+ybuf. MODE 2: BN+tanh.
template<int MODE>
__global__ __launch_bounds__(256) void conv2_body(
    const int* __restrict__ idxbuf, const float* __restrict__ proj,
    const float* __restrict__ c2b, const float* __restrict__ sAB2,
    float* __restrict__ part2, float* __restrict__ ybuf, float* __restrict__ yout) {
  __shared__ float xw[4][6];
  int t = threadIdx.x;
  int bx = blockIdx.x;
  int b = bx >> 6;
  int tile = bx & 63;
  int px = (tile & 1)*64 + (t & 63);
  int py = (tile >> 1)*4 + (t >> 6);
  const int* idxb = idxbuf + b*HP*WP;
  float acc[12];   // [(pa*2+pb)*3 + oc]
  #pragma unroll
  for (int i = 0; i < 12; ++i) acc[i] = 0.f;
  #pragma unroll
  for (int r = 0; r < 3; ++r) {
    int cy = py - 1 + r;
    bool vy = (cy >= 0) && (cy < HP);
    #pragma unroll
    for (int s = 0; s < 3; ++s) {
      int cx = px - 1 + s;
      if (!(vy && (cx >= 0) && (cx < WP))) continue;   // zero-pad cell
      int ii = idxb[cy*WP + cx];
      const float4* pr = (const float4*)(proj + (size_t)ii*64);
      #pragma unroll
      for (int rp = 0; rp < ((r==1) ? 2 : 1); ++rp) {
        const int pa = (r==0) ? 0 : (r==2) ? 1 : rp;
        const int ca = (r==0) ? 0 : (r==2) ? 1 : (1-rp);
        #pragma unroll
        for (int sp = 0; sp < ((s==1) ? 2 : 1); ++sp) {
          const int pb = (s==0) ? 0 : (s==2) ? 1 : sp;
          const int cb = (s==0) ? 0 : (s==2) ? 1 : (1-sp);
          float4 v = pr[pa*8 + pb*4 + ca*2 + cb];
          int ob = (pa*2 + pb)*3;
          acc[ob+0] += v.x;
          acc[ob+1] += v.y;
          acc[ob+2] += v.z;
        }
      }
    }
  }
  if (MODE == 2) {
    #pragma unroll
    for (int pa = 0; pa < 2; ++pa) {
      int yy = 2*py + pa;
      #pragma unroll
      for (int pb = 0; pb < 2; ++pb) {
        int xx = 2*px + pb;
        int ob = (pa*2 + pb)*3;
        float v0 = tanhf(fmaf(acc[ob+0], sAB2[0], sAB2[4]));
        float v1 = tanhf(fmaf(acc[ob+1], sAB2[1], sAB2[5]));
        float v2 = tanhf(fmaf(acc[ob+2], sAB2[2], sAB2[6]));
        yout[((size_t)(b*3 + 0)*HH + yy)*WW + xx] = v0;
        yout[((size_t)(b*3 + 1)*HH + yy)*WW + xx] = v1;
        yout[((size_t)(b*3 + 2)*HH + yy)*WW + xx] = v2;
      }
    }
  } else {
    float s0=0.f,s1=0.f,s2=0.f, q0=0.f,q1=0.f,q2=0.f;
    #pragma unroll
    for (int pa = 0; pa < 2; ++pa) {
      int yy = 2*py + pa;
      #pragma unroll
      for (int pb = 0; pb < 2; ++pb) {
        int xx = 2*px + pb;
        int ob = (pa*2 + pb)*3;
        float v0 = acc[ob+0] + c2b[0], v1 = acc[ob+1] + c2b[1], v2 = acc[ob+2] + c2b[2];
        s0 += v0; s1 += v1; s2 += v2;
        q0 = fmaf(v0, v0, q0); q1 = fmaf(v1, v1, q1); q2 = fmaf(v2, v2, q2);
        if (MODE == 1) {
          ybuf[((size_t)(b*3 + 0)*HH + yy)*WW + xx] = v0;
          ybuf[((size_t)(b*3 + 1)*HH + yy)*WW + xx] = v1;
          ybuf[((size_t)(b*3 + 2)*HH + yy)*WW + xx] = v2;
        }
      }
    }
    float sv[3] = {s0, s1, s2}, qv2[3] = {q0, q1, q2};
    #pragma unroll
    for (int oc = 0; oc < 3; ++oc) {
      float v = sv[oc], q = qv2[oc];
      #pragma unroll
      for (int m = 1; m < 64; m <<= 1) { v += __shfl_xor(v, m, 64); q += __shfl_xor(q, m, 64); }
      if ((t & 63) == 0) { xw[t >> 6][oc] = v; xw[t >> 6][3 + oc] = q; }
    }
    __syncthreads();
    if (t == 0) {
      #pragma unroll
      for (int i = 0; i < 6; ++i)
        part2[bx*6 + i] = (xw[0][i] + xw[1][i]) + (xw[2][i] + xw[3][i]);
    }
  }
}

// K7: reduce conv2 stats -> scale/bias (non-ybuf path only). fold_bias folds conv bias.
__global__ __launch_bounds__(256) void k7_reduce_bn2(
    const float* __restrict__ part2, const float* __restrict__ g2,
    const float* __restrict__ bt2, const float* __restrict__ c2b,
    float* __restrict__ sAB2, int fold_bias) {
  int t = threadIdx.x;
  int w = t >> 6, lane = t & 63;
  if (w >= 3) return;
  double s = 0.0, q = 0.0;
  for (int i = lane; i < 512; i += 64) {
    s += (double)part2[i*6 + w];
    q += (double)part2[i*6 + 3 + w];
  }
  #pragma unroll
  for (int m = 1; m < 64; m <<= 1) { s += __shfl_xor(s, m, 64); q += __shfl_xor(q, m, 64); }
  if (lane == 0) {
    double mean = s / (double)NPIX;
    double var  = q / (double)NPIX - mean*mean;
    double A = (double)g2[w] / sqrt(var + 1e-5);
    double Bc = (double)bt2[w] - mean*A;
    if (fold_bias) Bc += (double)c2b[w]*A;
    sAB2[w] = (float)A;
    sAB2[4 + w] = (float)Bc;
  }
}

// K8 v2: per-block sAB2 recompute (identical fixed-order reduction -> deterministic, L2-resident)
// + elementwise BN2+tanh from ybuf. grid 1536 x 256, float4. Replaces k7 in the ybuf path.
__global__ __launch_bounds__(256) void k8_apply(
    const float* __restrict__ part2, const float* __restrict__ g2,
    const float* __restrict__ bt2, const float* __restrict__ ybuf,
    float* __restrict__ yout) {
  __shared__ float sab[8];
  int t = threadIdx.x;
  int w = t >> 6, lane = t & 63;
  if (w < 3) {
    double s = 0.0, q = 0.0;
    for (int i = lane; i < 512; i += 64) {
      s += (double)part2[i*6 + w];
      q += (double)part2[i*6 + 3 + w];
    }
    #pragma unroll
    for (int m = 1; m < 64; m <<= 1) { s += __shfl_xor(s, m, 64); q += __shfl_xor(q, m, 64); }
    if (lane == 0) {
      double mean = s / (double)NPIX;
      double var  = q / (double)NPIX - mean*mean;
      double A = (double)g2[w] / sqrt(var + 1e-5);
      sab[w] = (float)A;
      sab[4 + w] = (float)((double)bt2[w] - mean*A);
    }
  }
  __syncthreads();
  int i4 = blockIdx.x*256 + t;
  int i = i4 * 4;
  int oc = (i >> 16) % 3;
  float A = sab[oc], B = sab[4 + oc];
  float4 v = *(const float4*)(ybuf + i);
  float4 r;
  r.x = tanhf(fmaf(v.x, A, B));
  r.y = tanhf(fmaf(v.y, A, B));
  r.z = tanhf(fmaf(v.z, A, B));
  r.w = tanhf(fmaf(v.w, A, B));
  *(float4*)(yout + i) = r;
}

extern "C" void kernel_launch(void* const* d_in, const int* in_sizes, int n_in,
                              void* d_out, int out_size, void* d_ws, size_t ws_size,
                              hipStream_t stream) {
  const float* x   = (const float*)d_in[0];
  const float* w1  = (const float*)d_in[1];
  const float* b1  = (const float*)d_in[2];
  const float* g1  = (const float*)d_in[3];
  const float* bt1 = (const float*)d_in[4];
  const float* emb = (const float*)d_in[5];
  const float* w2  = (const float*)d_in[6];
  const float* b2  = (const float*)d_in[7];
  const float* g2  = (const float*)d_in[8];
  const float* bt2 = (const float*)d_in[9];
  float* out = (float*)d_out;

  // workspace layout: base end 38,849,664 B. epack+proj overlay part1 (dead after k2).
  char* ws = (char*)d_ws;
  float*  pooled  = (float*) (ws);               // 33,554,432 (f32 raw-max, consumed by kB)
  double* part1   = (double*)(ws + 33554432);    //  4,194,304 (4096*128*8)
  char*   epack   =          (ws + 33554432);    //    262,144 (overlay, after k2)
  float*  proj    = (float*) (ws + 33816576);    //    262,144 (overlay, after k2)
  int*    idxbuf  = (int*)   (ws + 37748736);    //    524,288
  u32*    flagids = (u32*)   (ws + 38273024);    //    524,288
  u32*    flagcnt = (u32*)   (ws + 38797312);    //         64
  float*  part2   = (float*) (ws + 38799424);    //     12,288
  double* sAB1    = (double*)(ws + 38811712);    //      1,024
  float*  sAB2    = (float*) (ws + 38812736);    //         64
  double* enormd  = (double*)(ws + 38812800);    //      8,192
  float*  enf     = (float*) (ws + 38820992);    //      4,096
  float*  weff    = (float*) (ws + 38825088);    //     16,384
  double* lossq   = (double*)(ws + 38841472);    //      8,192 (1024*8) -> base end 38,849,664
  float*  ybuf    = (float*) (ws + 38849664);    //  6,291,456 -> end 45,141,120 (optional)
  bool use_ybuf = (ws_size >= (size_t)45141120);

  hipLaunchKernelGGL(k1_fused, dim3(4096), dim3(256), 0, stream, x, w1, b1, part1, pooled);
  hipLaunchKernelGGL(k2_reduce_bn1, dim3(80), dim3(256), 0, stream, part1, g1, bt1, sAB1, w2, weff);
  hipLaunchKernelGGL(kE_prep, dim3(260), dim3(256), 0, stream, emb, epack, enormd, enf, flagcnt, weff, proj);
  hipLaunchKernelGGL(kB_mfma, dim3(1024), dim3(256), 0, stream, pooled, sAB1, (const char*)epack,
                     enf, idxbuf, out, lossq, flagcnt, flagids);
  hipLaunchKernelGGL(kC_fallback, dim3(2049), dim3(64), 0, stream, x, w1, b1, sAB1, emb, enormd,
                     flagcnt, flagids, idxbuf, out, lossq);
  if (use_ybuf) {
    hipLaunchKernelGGL((conv2_body<1>), dim3(512), dim3(256), 0, stream, idxbuf, proj, b2, sAB2, part2, ybuf, out);
    hipLaunchKernelGGL(k8_apply, dim3(1536), dim3(256), 0, stream, part2, g2, bt2, ybuf, out);
  } else {
    hipLaunchKernelGGL((conv2_body<0>), dim3(512), dim3(256), 0, stream, idxbuf, proj, b2, sAB2, part2, ybuf, out);
    hipLaunchKernelGGL(k7_reduce_bn2, dim3(1), dim3(256), 0, stream, part2, g2, bt2, b2, sAB2, 1);
    hipLaunchKernelGGL((conv2_body<2>), dim3(512), dim3(256), 0, stream, idxbuf, proj, b2, sAB2, part2, ybuf, out);
  }
}

// Round 22
// 200.624 us; speedup vs baseline: 1.0143x; 1.0143x over previous
//
#include <hip/hip_runtime.h>
#include <hip/hip_bf16.h>
#include <math.h>

typedef unsigned int u32;
typedef unsigned short u16;
typedef __attribute__((ext_vector_type(8))) short short8v;   // 8 bf16 (4 VGPRs)
typedef __attribute__((ext_vector_type(4))) float f32x4;     // 4 fp32

#define HH 256
#define WW 256
#define HP 128
#define WP 128
#define NPTS (8*HP*WP)        // 131072 pooled points
#define NPIX 524288           // 8*256*256 per-channel pixel count (both BNs)
#define Y_ELEMS (8*3*HH*WW)   // 1572864
#define IDX_OFF Y_ELEMS
#define LOSS_OFF (Y_ELEMS + NPTS)
#define MARGIN_MFMA 0.05f     // sc-units; m-units flag threshold = MARGIN_MFMA/2

__device__ __forceinline__ u32 bfr(float f) {   // f32 -> bf16 bits (RNE)
  u32 u = __float_as_uint(f);
  return (u + 0x7FFFu + ((u >> 16) & 1u)) >> 16;
}
__device__ __forceinline__ float bff(u32 h) { return __uint_as_float(h << 16); }

// ============ K1: f32 conv1 (LDS-staged x) -> f64 BN-stats partials + pooled raw-max ============
__global__ __launch_bounds__(256) void k1_fused(
    const float* __restrict__ x, const float* __restrict__ w1,
    const float* __restrict__ b1, double* __restrict__ part1,
    float* __restrict__ pooled) {
  __shared__ float wl[27*64];     // [tap][ch]
  __shared__ float b1s[64];
  __shared__ float xs[3][4][68];  // [ic][row r][col j], zero-padded at edges
  __shared__ double sred[4][128];
  int t = threadIdx.x;
  for (int i = t; i < 27*64; i += 256) { int c = i & 63; int tap = i >> 6; wl[i] = w1[c*27 + tap]; }
  if (t < 64) b1s[t] = b1[t];
  int bx = blockIdx.x;
  int b = bx >> 9;
  int pid0 = (bx & 511) * 32;
  int py = pid0 >> 7;
  int px0 = pid0 & 127;
  int gcol0 = 2*px0 - 1, grow0 = 2*py - 1;
  for (int i = t; i < 816; i += 256) {          // 3*4*68
    int j = i % 68;
    int rr = (i / 68) & 3;
    int ic = i / 272;
    int col = gcol0 + j, row = grow0 + rr;
    float v = 0.f;
    if (col >= 0 && col < WW && row >= 0 && row < HH)
      v = x[((size_t)((b*3 + ic)*HH + row))*WW + col];
    xs[ic][rr][j] = v;
  }
  __syncthreads();
  int lpx = t >> 3;
  int co = (t & 7) * 8;
  float A0[8], A1[8], C0[8], C1[8];
  #pragma unroll
  for (int c = 0; c < 8; ++c) { float bb = b1s[co + c]; A0[c] = bb; A1[c] = bb; C0[c] = bb; C1[c] = bb; }
  #pragma unroll
  for (int ic = 0; ic < 3; ++ic) {
    #pragma unroll
    for (int dy = 0; dy < 3; ++dy) {
      const float* wb = wl + (size_t)((ic*3 + dy)*3)*64 + co;
      int j0 = 2*lpx;
      float xa0 = xs[ic][dy][j0+0], xa1 = xs[ic][dy][j0+1], xa2 = xs[ic][dy][j0+2], xa3 = xs[ic][dy][j0+3];
      float xc0 = xs[ic][dy+1][j0+0], xc1 = xs[ic][dy+1][j0+1], xc2 = xs[ic][dy+1][j0+2], xc3 = xs[ic][dy+1][j0+3];
      #pragma unroll
      for (int c = 0; c < 8; ++c) {
        float w0 = wb[c], w1v = wb[64 + c], w2v = wb[128 + c];
        A0[c] = fmaf(xa0, w0, fmaf(xa1, w1v, fmaf(xa2, w2v, A0[c])));
        A1[c] = fmaf(xa1, w0, fmaf(xa2, w1v, fmaf(xa3, w2v, A1[c])));
        C0[c] = fmaf(xc0, w0, fmaf(xc1, w1v, fmaf(xc2, w2v, C0[c])));
        C1[c] = fmaf(xc1, w0, fmaf(xc2, w1v, fmaf(xc3, w2v, C1[c])));
      }
    }
  }
  double s[8], q[8];
  float m[8];
  #pragma unroll
  for (int c = 0; c < 8; ++c) {
    double dA0 = (double)A0[c], dA1 = (double)A1[c], dC0 = (double)C0[c], dC1 = (double)C1[c];
    double s_ = 0.0;
    s_ += dA0 + dA1;
    double q_ = fma(dA0, dA0, 0.0);
    q_ = fma(dA1, dA1, q_);
    float m_ = fmaxf(-3.4e38f, fmaxf(A0[c], A1[c]));
    s_ += dC0 + dC1;
    q_ = fma(dC0, dC0, q_);
    q_ = fma(dC1, dC1, q_);
    m_ = fmaxf(m_, fmaxf(C0[c], C1[c]));
    s[c] = s_; q[c] = q_; m[c] = m_;
  }
  int pid = pid0 + lpx;
  size_t p = (size_t)b*16384 + pid;
  *(float4*)(pooled + p*64 + co)     = make_float4(m[0], m[1], m[2], m[3]);
  *(float4*)(pooled + p*64 + co + 4) = make_float4(m[4], m[5], m[6], m[7]);
  #pragma unroll 1
  for (int c = 0; c < 8; ++c) {
    #pragma unroll
    for (int st = 8; st < 64; st <<= 1) {
      s[c] += __shfl_xor(s[c], st, 64);
      q[c] += __shfl_xor(q[c], st, 64);
    }
  }
  int w = t >> 6;
  if ((t & 63) < 8) {
    #pragma unroll
    for (int c = 0; c < 8; ++c) {
      sred[w][co + c] = s[c];
      sred[w][64 + co + c] = q[c];
    }
  }
  __syncthreads();
  if (t < 128)
    part1[(size_t)bx*128 + t] = (sred[0][t] + sred[1][t]) + (sred[2][t] + sred[3][t]);
}

// K2: blocks 0-63: reduce 4096 block-partials (f64) -> A,B per channel.
// blocks 64-79: build weff[combo16][ic64][oc4] from w2 (independent of part1). grid 80.
__global__ __launch_bounds__(256) void k2_reduce_bn1(
    const double* __restrict__ part1, const float* __restrict__ gamma,
    const float* __restrict__ beta, double* __restrict__ sAB1,
    const float* __restrict__ w2, float* __restrict__ weff) {
  int bx = blockIdx.x;
  if (bx >= 64) {
    int e = (bx - 64)*256 + threadIdx.x;
    int oc = e & 3;
    int ic = (e >> 2) & 63;
    int combo = e >> 8;
    if (oc == 3) { weff[e] = 0.f; return; }
    int bq = combo & 1, a = (combo >> 1) & 1, ex = (combo >> 2) & 1, ey = combo >> 3;
    int rs = (a == 0) ? 0 : (ey == 0 ? 1 : 2);
    int rc = ((a ^ ey) != 0) ? 2 : 1;
    int cs = (bq == 0) ? 0 : (ex == 0 ? 1 : 2);
    int cc = ((bq ^ ex) != 0) ? 2 : 1;
    float ssum = 0.f;
    for (int i = 0; i < rc; ++i)
      for (int j = 0; j < cc; ++j)
        ssum += w2[((oc*64 + ic)*3 + (rs + i))*3 + (cs + j)];
    weff[e] = ssum;
    return;
  }
  int c = bx, t = threadIdx.x;
  double s = 0.0, q = 0.0;
  for (int i = t; i < 4096; i += 256) {
    const double* p = part1 + (size_t)i*128;
    s += p[c];
    q += p[64 + c];
  }
  __shared__ double ls[256], lq[256];
  ls[t] = s; lq[t] = q;
  __syncthreads();
  for (int o = 128; o > 0; o >>= 1) {
    if (t < o) { ls[t] += ls[t+o]; lq[t] += lq[t+o]; }
    __syncthreads();
  }
  if (t == 0) {
    double mean = ls[0] / (double)NPIX;
    double var  = lq[0] / (double)NPIX - mean*mean;
    double A = (double)gamma[c] / sqrt(var + 1e-5);
    sAB1[c] = A;
    sAB1[64 + c] = (double)beta[c] - mean*A;
  }
}

// kE_prep: blocks 0-3: embed -> tile-fragment-lane-linear bf16 hi/lo pack + enormd + enf
// (+flagcnt zero). blocks 4-259: proj table (reads weff from k2). grid 260 x 256.
__global__ void kE_prep(const float* __restrict__ embed, char* __restrict__ epack,
                        double* __restrict__ enormd, float* __restrict__ enf,
                        u32* __restrict__ flagcnt,
                        const float* __restrict__ weff, float* __restrict__ proj) {
  int bxx = blockIdx.x;
  if (bxx >= 4) {
    // proj[k][combo][oc] = sum_ic embed[k][ic]*weff[combo][ic][oc]; oc=3 pad -> 0.
    int e = (bxx - 4)*256 + threadIdx.x;
    int k = e >> 6;
    int slot = e & 63;
    int combo = slot >> 2, oc = slot & 3;
    if (oc == 3) { proj[e] = 0.f; return; }
    const float* er = embed + (size_t)k*64;
    const float* wc = weff + combo*256 + oc;
    float s0 = 0.f, s1 = 0.f;
    #pragma unroll 8
    for (int ic = 0; ic < 64; ic += 2) {
      s0 = fmaf(er[ic],     wc[ic*4],     s0);
      s1 = fmaf(er[ic + 1], wc[ic*4 + 4], s1);
    }
    proj[e] = s0 + s1;
    return;
  }
  if (bxx == 0 && threadIdx.x == 0) flagcnt[0] = 0u;
  int k = bxx*256 + threadIdx.x;
  const float4* e4 = (const float4*)(embed + (size_t)k*64);
  u32 hw[32], lw[32];
  double s0 = 0.0, s1 = 0.0;
  #pragma unroll
  for (int i = 0; i < 16; ++i) {
    float4 v = e4[i];
    float f0 = v.x, f1 = v.y, f2 = v.z, f3 = v.w;
    s0 = fma((double)f0, (double)f0, s0); s1 = fma((double)f1, (double)f1, s1);
    s0 = fma((double)f2, (double)f2, s0); s1 = fma((double)f3, (double)f3, s1);
    u32 h0 = bfr(f0), h1 = bfr(f1), h2 = bfr(f2), h3 = bfr(f3);
    u32 l0 = bfr(f0 - bff(h0)), l1 = bfr(f1 - bff(h1));
    u32 l2 = bfr(f2 - bff(h2)), l3 = bfr(f3 - bff(h3));
    hw[2*i]   = h0 | (h1 << 16);
    hw[2*i+1] = h2 | (h3 << 16);
    lw[2*i]   = l0 | (l1 << 16);
    lw[2*i+1] = l2 | (l3 << 16);
  }
  char* tb = epack + (size_t)(k >> 4)*4096 + (size_t)(k & 15)*16;
  #pragma unroll
  for (int g = 0; g < 4; ++g) {
    *(uint4*)(tb + 0*1024 + g*256) = make_uint4(hw[4*g+0], hw[4*g+1], hw[4*g+2], hw[4*g+3]);
    *(uint4*)(tb + 1*1024 + g*256) = make_uint4(hw[16+4*g+0], hw[16+4*g+1], hw[16+4*g+2], hw[16+4*g+3]);
    *(uint4*)(tb + 2*1024 + g*256) = make_uint4(lw[4*g+0], lw[4*g+1], lw[4*g+2], lw[4*g+3]);
    *(uint4*)(tb + 3*1024 + g*256) = make_uint4(lw[16+4*g+0], lw[16+4*g+1], lw[16+4*g+2], lw[16+4*g+3]);
  }
  double e = s0 + s1;
  enormd[k] = e;
  enf[k] = (float)e;
}

// KB-MFMA v9: fused feature pack + 4-tiles-per-barrier B staging + med3 tracking + setprio.
#define MFMA_BF16 __builtin_amdgcn_mfma_f32_16x16x32_bf16
#define PROC_T(ntv) { \
  int code = (ntv)*16 + col; \
  float en2 = senf[code];   /* pre-negated-halved: -en/2 */ \
  f32x4 accA0={en2,en2,en2,en2}, accA1={0.f,0.f,0.f,0.f}; \
  f32x4 accB0={en2,en2,en2,en2}, accB1={0.f,0.f,0.f,0.f}; \
  __builtin_amdgcn_s_setprio(1); \
  accA0 = MFMA_BF16(aA_h0, b_h0, accA0, 0, 0, 0); \
  accA1 = MFMA_BF16(aA_h1, b_h1, accA1, 0, 0, 0); \
  accB0 = MFMA_BF16(aB_h0, b_h0, accB0, 0, 0, 0); \
  accB1 = MFMA_BF16(aB_h1, b_h1, accB1, 0, 0, 0); \
  accA0 = MFMA_BF16(aA_l0, b_h0, accA0, 0, 0, 0); \
  accA1 = MFMA_BF16(aA_l1, b_h1, accA1, 0, 0, 0); \
  accB0 = MFMA_BF16(aB_l0, b_h0, accB0, 0, 0, 0); \
  accB1 = MFMA_BF16(aB_l1, b_h1, accB1, 0, 0, 0); \
  accA0 = MFMA_BF16(aA_h0, b_l0, accA0, 0, 0, 0); \
  accA1 = MFMA_BF16(aA_h1, b_l1, accA1, 0, 0, 0); \
  accB0 = MFMA_BF16(aB_h0, b_l0, accB0, 0, 0, 0); \
  accB1 = MFMA_BF16(aB_h1, b_l1, accB1, 0, 0, 0); \
  __builtin_amdgcn_s_setprio(0); \
  _Pragma("unroll") \
  for (int j = 0; j < 4; ++j) { \
    float mA = accA0[j] + accA1[j]; \
    bool cA = mA > bestA[j]; \
    b2A[j] = __builtin_amdgcn_fmed3f(b2A[j], mA, bestA[j]);  /* b2<=best => median == max(b2,min(m,best)) */ \
    bestA[j] = fmaxf(bestA[j], mA); \
    idxA[j] = cA ? code : idxA[j]; \
    float mB = accB0[j] + accB1[j]; \
    bool cB = mB > bestB[j]; \
    b2B[j] = __builtin_amdgcn_fmed3f(b2B[j], mB, bestB[j]); \
    bestB[j] = fmaxf(bestB[j], mB); \
    idxB[j] = cB ? code : idxB[j]; \
  } \
}
#define PROC_LDS(bb, ntv) { \
  short8v b_h0 = *(const short8v*)((bb) + 0*1024 + lane*16); \
  short8v b_h1 = *(const short8v*)((bb) + 1*1024 + lane*16); \
  short8v b_l0 = *(const short8v*)((bb) + 2*1024 + lane*16); \
  short8v b_l1 = *(const short8v*)((bb) + 3*1024 + lane*16); \
  PROC_T(ntv); \
}

__global__ __launch_bounds__(256) void kB_mfma(
    const float* __restrict__ pooled, const double* __restrict__ sAB1,
    const char* __restrict__ epack, const float* __restrict__ enf,
    int* __restrict__ idxbuf, float* __restrict__ out_f, double* __restrict__ lossq,
    u32* __restrict__ flagcnt, u32* __restrict__ flagids) {
  __shared__ float senf[1024];
  __shared__ char shbuf[32768];   // phase1: 128 pts x 256B features; phase2: btile[2][4][4096]
  __shared__ float fnp[256];
  __shared__ float fnsum[128];
  __shared__ float sAs[64], sBs[64];
  __shared__ double wred[4];
  int t = threadIdx.x;
  for (int i = t; i < 1024; i += 256) senf[i] = -0.5f * enf[i];
  if (t < 64) { sAs[t] = (float)sAB1[t]; sBs[t] = (float)sAB1[64 + t]; }
  __syncthreads();
  // ---- phase 1: feature BN+relu+bf16 hi/lo split for this block's 128 points, staged in LDS ----
  {
    int lp = t >> 1, h = t & 1, cb = h*32;
    int p = blockIdx.x*128 + lp;
    const float4* src = (const float4*)(pooled + (size_t)p*64 + cb);
    float fn = 0.f;
    u32 hw[16], lw[16];
    #pragma unroll
    for (int i = 0; i < 8; ++i) {
      float4 v = src[i];
      float f0 = fmaxf(fmaf(v.x, sAs[cb+4*i+0], sBs[cb+4*i+0]), 0.f);
      float f1 = fmaxf(fmaf(v.y, sAs[cb+4*i+1], sBs[cb+4*i+1]), 0.f);
      float f2 = fmaxf(fmaf(v.z, sAs[cb+4*i+2], sBs[cb+4*i+2]), 0.f);
      float f3 = fmaxf(fmaf(v.w, sAs[cb+4*i+3], sBs[cb+4*i+3]), 0.f);
      fn = fmaf(f0, f0, fn); fn = fmaf(f1, f1, fn);
      fn = fmaf(f2, f2, fn); fn = fmaf(f3, f3, fn);
      u32 h0 = bfr(f0), h1 = bfr(f1), h2 = bfr(f2), h3 = bfr(f3);
      u32 l0 = bfr(f0 - bff(h0)), l1 = bfr(f1 - bff(h1));
      u32 l2 = bfr(f2 - bff(h2)), l3 = bfr(f3 - bff(h3));
      hw[2*i]   = h0 | (h1 << 16);
      hw[2*i+1] = h2 | (h3 << 16);
      lw[2*i]   = l0 | (l1 << 16);
      lw[2*i+1] = l2 | (l3 << 16);
    }
    uint4* dh = (uint4*)(shbuf + (size_t)lp*256 + h*64);        // hi half (point-major layout)
    uint4* dl = (uint4*)(shbuf + (size_t)lp*256 + 128 + h*64);  // lo half
    #pragma unroll
    for (int i = 0; i < 4; ++i) dh[i] = make_uint4(hw[4*i], hw[4*i+1], hw[4*i+2], hw[4*i+3]);
    #pragma unroll
    for (int i = 0; i < 4; ++i) dl[i] = make_uint4(lw[4*i], lw[4*i+1], lw[4*i+2], lw[4*i+3]);
    fnp[t] = fn;
  }
  __syncthreads();
  if ((t & 1) == 0) fnsum[t >> 1] = fnp[t] + fnp[t + 1];
  // ---- A fragments from staged features ----
  int lane = t & 63;
  int col = lane & 15, g = lane >> 4;
  int w = t >> 6;
  const char* fbA = shbuf + (size_t)(w*32 + col)*256 + 16*g;
  const char* fbB = shbuf + (size_t)(w*32 + 16 + col)*256 + 16*g;
  short8v aA_h0 = *(const short8v*)(fbA);
  short8v aA_h1 = *(const short8v*)(fbA + 64);
  short8v aA_l0 = *(const short8v*)(fbA + 128);
  short8v aA_l1 = *(const short8v*)(fbA + 192);
  short8v aB_h0 = *(const short8v*)(fbB);
  short8v aB_h1 = *(const short8v*)(fbB + 64);
  short8v aB_l0 = *(const short8v*)(fbB + 128);
  short8v aB_l1 = *(const short8v*)(fbB + 192);
  __syncthreads();   // all fragment reads + fnsum writes done before shbuf reuse as btile
  char (*btile)[4][4096] = (char (*)[4][4096])shbuf;   // double-buffered 4-tile group (64 codes)
  float bestA[4], b2A[4], bestB[4], b2B[4];
  int idxA[4], idxB[4];
  #pragma unroll
  for (int j = 0; j < 4; ++j) {
    bestA[j] = -3.4e38f; b2A[j] = -3.4e38f; idxA[j] = 0;
    bestB[j] = -3.4e38f; b2B[j] = -3.4e38f; idxB[j] = 0;
  }
  // prologue: stage group 0 (tiles 0..3)
  #pragma unroll
  for (int k = 0; k < 4; ++k)
    *(uint4*)(&btile[0][k][t*16]) = *(const uint4*)(epack + (size_t)k*4096 + (size_t)t*16);
  __syncthreads();
  #pragma unroll 1
  for (int ng = 0; ng < 16; ++ng) {
    int cur = ng & 1;
    uint4 stg0, stg1, stg2, stg3;
    if (ng < 15) {
      const char* base = epack + (size_t)(4*ng + 4)*4096 + (size_t)t*16;
      stg0 = *(const uint4*)(base);             // issue early — latency hidden under 4x PROC
      stg1 = *(const uint4*)(base + 4096);
      stg2 = *(const uint4*)(base + 8192);
      stg3 = *(const uint4*)(base + 12288);
    }
    PROC_LDS(&btile[cur][0][0], 4*ng + 0);
    PROC_LDS(&btile[cur][1][0], 4*ng + 1);
    PROC_LDS(&btile[cur][2][0], 4*ng + 2);
    PROC_LDS(&btile[cur][3][0], 4*ng + 3);
    if (ng < 15) {
      *(uint4*)(&btile[cur ^ 1][0][t*16]) = stg0;   // write-late
      *(uint4*)(&btile[cur ^ 1][1][t*16]) = stg1;
      *(uint4*)(&btile[cur ^ 1][2][t*16]) = stg2;
      *(uint4*)(&btile[cur ^ 1][3][t*16]) = stg3;
    }
    __syncthreads();
  }
  // cross-lane reduce over 16 col-lanes per row-group (maximize m; lowest idx on ties = np rule)
  double lsum = 0.0;
  #pragma unroll
  for (int grp = 0; grp < 2; ++grp) {
    #pragma unroll
    for (int j = 0; j < 4; ++j) {
      float b  = (grp == 0) ? bestA[j] : bestB[j];
      float s2 = (grp == 0) ? b2A[j]   : b2B[j];
      int  id  = (grp == 0) ? idxA[j]  : idxB[j];
      #pragma unroll
      for (int m = 1; m < 16; m <<= 1) {
        float ob  = __shfl_xor(b, m, 64);
        float os2 = __shfl_xor(s2, m, 64);
        int  oid  = __shfl_xor(id, m, 64);
        s2 = fmaxf(fmaxf(s2, os2), fminf(b, ob));
        if (ob > b || (ob == b && oid < id)) { b = ob; id = oid; }
      }
      if (col == 0) {
        int lpt = w*32 + grp*16 + g*4 + j;
        int p = blockIdx.x*128 + lpt;
        idxbuf[p] = id;
        out_f[IDX_OFF + p] = (float)id;
        lsum += (double)fmaf(-2.f, b, fnsum[lpt]);   // fn + (en - 2 dot)
        if (b - s2 <= 0.5f*MARGIN_MFMA) { u32 pos = atomicAdd(flagcnt, 1u); flagids[pos] = (u32)p; }
      }
    }
  }
  // block loss reduce (fixed-order butterfly, deterministic)
  #pragma unroll
  for (int m = 1; m < 64; m <<= 1) lsum += __shfl_xor(lsum, m, 64);
  if (lane == 0) wred[w] = lsum;
  __syncthreads();
  if (t == 0) lossq[blockIdx.x] = (wred[0] + wred[1]) + (wred[2] + wred[3]);
}

// KC: exact f64 resolution for flagged near-tie points + loss finalize (last block).
// grid 2049 x 64: blocks 0..2047 grid-stride flagged points; block 2048 reduces lossq.
__global__ __launch_bounds__(64) void kC_fallback(
    const float* __restrict__ x, const float* __restrict__ w1,
    const float* __restrict__ b1, const double* __restrict__ sAB1,
    const float* __restrict__ embed, const double* __restrict__ enormd,
    const u32* __restrict__ flagcnt, const u32* __restrict__ flagids,
    int* __restrict__ idxbuf, float* __restrict__ out_f,
    const double* __restrict__ lossq) {
  int lane = threadIdx.x;
  if (blockIdx.x == gridDim.x - 1) {   // loss finalize (deterministic fixed order)
    double s = 0.0;
    for (int i = lane; i < 1024; i += 64) s += lossq[i];
    #pragma unroll
    for (int st = 1; st < 64; st <<= 1) s += __shfl_xor(s, st, 64);
    if (lane == 0) out_f[LOSS_OFF] = (float)(0.25 * s / (double)((size_t)NPTS * 64));
    return;
  }
  __shared__ double fd[64];
  double wv[27];
  #pragma unroll
  for (int i = 0; i < 27; ++i) wv[i] = (double)w1[lane*27 + i];
  double bias = (double)b1[lane];
  double A = sAB1[lane], B = sAB1[64 + lane];
  u32 n = flagcnt[0];
  u32 stride = gridDim.x - 1;
  for (u32 i = blockIdx.x; i < n; i += stride) {
    int p = (int)flagids[i];
    int b = p >> 14, py = (p >> 7) & 127, px = p & 127;
    double mx = -1e300;
    #pragma unroll
    for (int ry = 0; ry < 2; ++ry) {
      #pragma unroll
      for (int cx = 0; cx < 2; ++cx) {
        double a = bias;
        int yy = 2*py + ry, xx = 2*px + cx;
        #pragma unroll
        for (int ic = 0; ic < 3; ++ic) {
          #pragma unroll
          for (int dy = 0; dy < 3; ++dy) {
            int ryy = yy + dy - 1;
            if (ryy >= 0 && ryy < HH) {
              const float* row = x + ((size_t)((b*3 + ic)*HH + ryy))*WW;
              #pragma unroll
              for (int dxx = 0; dxx < 3; ++dxx) {
                int xc = xx + dxx - 1;
                if (xc >= 0 && xc < WW) a = fma((double)row[xc], wv[(ic*3 + dy)*3 + dxx], a);
              }
            }
          }
        }
        mx = fmax(mx, a);
      }
    }
    fd[lane] = fmax(fma(mx, A, B), 0.0);
    __syncthreads();
    double bd = 1e300; int bk = 1 << 20;
    for (int kk = 0; kk < 16; ++kk) {
      int k = kk*64 + lane;
      const float* e = embed + (size_t)k*64;
      double e0=0,e1=0,e2=0,e3=0;
      #pragma unroll
      for (int d = 0; d < 16; ++d) {
        e0 = fma(fd[4*d+0], (double)e[4*d+0], e0);
        e1 = fma(fd[4*d+1], (double)e[4*d+1], e1);
        e2 = fma(fd[4*d+2], (double)e[4*d+2], e2);
        e3 = fma(fd[4*d+3], (double)e[4*d+3], e3);
      }
      double dist = fma(-2.0, (e0+e1)+(e2+e3), enormd[k]);
      if (dist < bd) { bd = dist; bk = k; }
    }
    #pragma unroll
    for (int st = 1; st < 64; st <<= 1) {
      double od = __shfl_xor(bd, st, 64);
      int ok = __shfl_xor(bk, st, 64);
      if (od < bd || (od == bd && ok < bk)) { bd = od; bk = ok; }
    }
    if (lane == 0) {
      idxbuf[p] = bk;
      out_f[IDX_OFF + p] = (float)bk;
    }
    __syncthreads();
  }
}

// conv2 v4: per-cell proj-table lookup. MODE 0: stats. MODE 1: stats+ybuf. MODE 2: BN+tanh.
template<int MODE>
__global__ __launch_bounds__(256) void conv2_body(
    const int* __restrict__ idxbuf, const float* __restrict__ proj,
    const float* __restrict__ c2b, const float* __restrict__ sAB2,
    float* __restrict__ part2, float* __restrict__ ybuf, float* __restrict__ yout) {
  __shared__ float xw[4][6];
  int t = threadIdx.x;
  int bx = blockIdx.x;
  int b = bx >> 6;
  int tile = bx & 63;
  int px = (tile & 1)*64 + (t & 63);
  int py = (tile >> 1)*4 + (t >> 6);
  const int* idxb = idxbuf + b*HP*WP;
  float acc[12];   // [(pa*2+pb)*3 + oc]
  #pragma unroll
  for (int i = 0; i < 12; ++i) acc[i] = 0.f;
  #pragma unroll
  for (int r = 0; r < 3; ++r) {
    int cy = py - 1 + r;
    bool vy = (cy >= 0) && (cy < HP);
    #pragma unroll
    for (int s = 0; s < 3; ++s) {
      int cx = px - 1 + s;
      if (!(vy && (cx >= 0) && (cx < WP))) continue;   // zero-pad cell
      int ii = idxb[cy*WP + cx];
      const float4* pr = (const float4*)(proj + (size_t)ii*64);
      #pragma unroll
      for (int rp = 0; rp < ((r==1) ? 2 : 1); ++rp) {
        const int pa = (r==0) ? 0 : (r==2) ? 1 : rp;
        const int ca = (r==0) ? 0 : (r==2) ? 1 : (1-rp);
        #pragma unroll
        for (int sp = 0; sp < ((s==1) ? 2 : 1); ++sp) {
          const int pb = (s==0) ? 0 : (s==2) ? 1 : sp;
          const int cb = (s==0) ? 0 : (s==2) ? 1 : (1-sp);
          float4 v = pr[pa*8 + pb*4 + ca*2 + cb];
          int ob = (pa*2 + pb)*3;
          acc[ob+0] += v.x;
          acc[ob+1] += v.y;
          acc[ob+2] += v.z;
        }
      }
    }
  }
  if (MODE == 2) {
    #pragma unroll
    for (int pa = 0; pa < 2; ++pa) {
      int yy = 2*py + pa;
      #pragma unroll
      for (int pb = 0; pb < 2; ++pb) {
        int xx = 2*px + pb;
        int ob = (pa*2 + pb)*3;
        float v0 = tanhf(fmaf(acc[ob+0], sAB2[0], sAB2[4]));
        float v1 = tanhf(fmaf(acc[ob+1], sAB2[1], sAB2[5]));
        float v2 = tanhf(fmaf(acc[ob+2], sAB2[2], sAB2[6]));
        yout[((size_t)(b*3 + 0)*HH + yy)*WW + xx] = v0;
        yout[((size_t)(b*3 + 1)*HH + yy)*WW + xx] = v1;
        yout[((size_t)(b*3 + 2)*HH + yy)*WW + xx] = v2;
      }
    }
  } else {
    float s0=0.f,s1=0.f,s2=0.f, q0=0.f,q1=0.f,q2=0.f;
    #pragma unroll
    for (int pa = 0; pa < 2; ++pa) {
      int yy = 2*py + pa;
      #pragma unroll
      for (int pb = 0; pb < 2; ++pb) {
        int xx = 2*px + pb;
        int ob = (pa*2 + pb)*3;
        float v0 = acc[ob+0] + c2b[0], v1 = acc[ob+1] + c2b[1], v2 = acc[ob+2] + c2b[2];
        s0 += v0; s1 += v1; s2 += v2;
        q0 = fmaf(v0, v0, q0); q1 = fmaf(v1, v1, q1); q2 = fmaf(v2, v2, q2);
        if (MODE == 1) {
          ybuf[((size_t)(b*3 + 0)*HH + yy)*WW + xx] = v0;
          ybuf[((size_t)(b*3 + 1)*HH + yy)*WW + xx] = v1;
          ybuf[((size_t)(b*3 + 2)*HH + yy)*WW + xx] = v2;
        }
      }
    }
    float sv[3] = {s0, s1, s2}, qv2[3] = {q0, q1, q2};
    #pragma unroll
    for (int oc = 0; oc < 3; ++oc) {
      float v = sv[oc], q = qv2[oc];
      #pragma unroll
      for (int m = 1; m < 64; m <<= 1) { v += __shfl_xor(v, m, 64); q += __shfl_xor(q, m, 64); }
      if ((t & 63) == 0) { xw[t >> 6][oc] = v; xw[t >> 6][3 + oc] = q; }
    }
    __syncthreads();
    if (t == 0) {
      #pragma unroll
      for (int i = 0; i < 6; ++i)
        part2[bx*6 + i] = (xw[0][i] + xw[1][i]) + (xw[2][i] + xw[3][i]);
    }
  }
}

// K7: reduce conv2 stats -> scale/bias. fold_bias=1 when the apply pass sees raw acc.
__global__ __launch_bounds__(256) void k7_reduce_bn2(
    const float* __restrict__ part2, const float* __restrict__ g2,
    const float* __restrict__ bt2, const float* __restrict__ c2b,
    float* __restrict__ sAB2, int fold_bias) {
  int t = threadIdx.x;
  int w = t >> 6, lane = t & 63;
  if (w >= 3) return;
  double s = 0.0, q = 0.0;
  for (int i = lane; i < 512; i += 64) {
    s += (double)part2[i*6 + w];
    q += (double)part2[i*6 + 3 + w];
  }
  #pragma unroll
  for (int m = 1; m < 64; m <<= 1) { s += __shfl_xor(s, m, 64); q += __shfl_xor(q, m, 64); }
  if (lane == 0) {
    double mean = s / (double)NPIX;
    double var  = q / (double)NPIX - mean*mean;
    double A = (double)g2[w] / sqrt(var + 1e-5);
    double Bc = (double)bt2[w] - mean*A;
    if (fold_bias) Bc += (double)c2b[w]*A;
    sAB2[w] = (float)A;
    sAB2[4 + w] = (float)Bc;
  }
}

// K8: elementwise BN2+tanh from ybuf. grid 1536 x 256, float4.
__global__ __launch_bounds__(256) void k8_apply(
    const float* __restrict__ ybuf, const float* __restrict__ sAB2,
    float* __restrict__ yout) {
  int i4 = blockIdx.x*256 + threadIdx.x;
  int i = i4 * 4;
  int oc = (i >> 16) % 3;
  float A = sAB2[oc], B = sAB2[4 + oc];
  float4 v = *(const float4*)(ybuf + i);
  float4 r;
  r.x = tanhf(fmaf(v.x, A, B));
  r.y = tanhf(fmaf(v.y, A, B));
  r.z = tanhf(fmaf(v.z, A, B));
  r.w = tanhf(fmaf(v.w, A, B));
  *(float4*)(yout + i) = r;
}

extern "C" void kernel_launch(void* const* d_in, const int* in_sizes, int n_in,
                              void* d_out, int out_size, void* d_ws, size_t ws_size,
                              hipStream_t stream) {
  const float* x   = (const float*)d_in[0];
  const float* w1  = (const float*)d_in[1];
  const float* b1  = (const float*)d_in[2];
  const float* g1  = (const float*)d_in[3];
  const float* bt1 = (const float*)d_in[4];
  const float* emb = (const float*)d_in[5];
  const float* w2  = (const float*)d_in[6];
  const float* b2  = (const float*)d_in[7];
  const float* g2  = (const float*)d_in[8];
  const float* bt2 = (const float*)d_in[9];
  float* out = (float*)d_out;

  // workspace layout: base end 38,849,664 B. epack+proj overlay part1 (dead after k2).
  char* ws = (char*)d_ws;
  float*  pooled  = (float*) (ws);               // 33,554,432 (f32 raw-max, consumed by kB)
  double* part1   = (double*)(ws + 33554432);    //  4,194,304 (4096*128*8)
  char*   epack   =          (ws + 33554432);    //    262,144 (overlay, after k2)
  float*  proj    = (float*) (ws + 33816576);    //    262,144 (overlay, after k2)
  int*    idxbuf  = (int*)   (ws + 37748736);    //    524,288
  u32*    flagids = (u32*)   (ws + 38273024);    //    524,288
  u32*    flagcnt = (u32*)   (ws + 38797312);    //         64
  float*  part2   = (float*) (ws + 38799424);    //     12,288
  double* sAB1    = (double*)(ws + 38811712);    //      1,024
  float*  sAB2    = (float*) (ws + 38812736);    //         64
  double* enormd  = (double*)(ws + 38812800);    //      8,192
  float*  enf     = (float*) (ws + 38820992);    //      4,096
  float*  weff    = (float*) (ws + 38825088);    //     16,384
  double* lossq   = (double*)(ws + 38841472);    //      8,192 (1024*8) -> base end 38,849,664
  float*  ybuf    = (float*) (ws + 38849664);    //  6,291,456 -> end 45,141,120 (optional)
  bool use_ybuf = (ws_size >= (size_t)45141120);

  hipLaunchKernelGGL(k1_fused, dim3(4096), dim3(256), 0, stream, x, w1, b1, part1, pooled);
  hipLaunchKernelGGL(k2_reduce_bn1, dim3(80), dim3(256), 0, stream, part1, g1, bt1, sAB1, w2, weff);
  hipLaunchKernelGGL(kE_prep, dim3(260), dim3(256), 0, stream, emb, epack, enormd, enf, flagcnt, weff, proj);
  hipLaunchKernelGGL(kB_mfma, dim3(1024), dim3(256), 0, stream, pooled, sAB1, (const char*)epack,
                     enf, idxbuf, out, lossq, flagcnt, flagids);
  hipLaunchKernelGGL(kC_fallback, dim3(2049), dim3(64), 0, stream, x, w1, b1, sAB1, emb, enormd,
                     flagcnt, flagids, idxbuf, out, lossq);
  if (use_ybuf) {
    hipLaunchKernelGGL((conv2_body<1>), dim3(512), dim3(256), 0, stream, idxbuf, proj, b2, sAB2, part2, ybuf, out);
    hipLaunchKernelGGL(k7_reduce_bn2, dim3(1), dim3(256), 0, stream, part2, g2, bt2, b2, sAB2, 0);
    hipLaunchKernelGGL(k8_apply, dim3(1536), dim3(256), 0, stream, ybuf, sAB2, out);
  } else {
    hipLaunchKernelGGL((conv2_body<0>), dim3(512), dim3(256), 0, stream, idxbuf, proj, b2, sAB2, part2, ybuf, out);
    hipLaunchKernelGGL(k7_reduce_bn2, dim3(1), dim3(256), 0, stream, part2, g2, bt2, b2, sAB2, 1);
    hipLaunchKernelGGL((conv2_body<2>), dim3(512), dim3(256), 0, stream, idxbuf, proj, b2, sAB2, part2, ybuf, out);
  }
}